// Round 1
// baseline (2659.923 us; speedup 1.0000x reference)
//
#include <hip/hip_runtime.h>
#include <hip/hip_bf16.h>
#include <math.h>

#define B_    32
#define T_    32
#define L_    64
#define EMB_  256
#define HID_  512
#define G4_   2048   // 4*HID
#define V_    30000
#define NOBJ_ 91
#define NROWS 1024   // T_*B_

__device__ __forceinline__ float sigmoidf_(float x) { return 1.0f / (1.0f + expf(-x)); }

// ---------------- kernel 1: gather embeddings, time-major X[n][256], n = t*32+b
__global__ void k_gather(const float* __restrict__ features,
                         const int*   __restrict__ captions,
                         const float* __restrict__ embed_W,
                         float* __restrict__ X) {
  int n = blockIdx.x, e = threadIdx.x;          // 1024 blocks x 256 threads
  int t = n >> 5, b = n & 31;
  float v;
  if (t == 0) v = features[b * EMB_ + e];
  else        v = embed_W[captions[b * T_ + (t - 1)] * EMB_ + e];
  X[n * EMB_ + e] = v;
}

// ---------------- kernel 2: transpose W_hh [2048][512] -> W_hhT [512][2048]
__global__ void k_transpose(const float* __restrict__ W, float* __restrict__ WT) {
  __shared__ float s[32][33];
  int k0 = blockIdx.x * 32;   // k tile
  int r0 = blockIdx.y * 32;   // r tile
  int tx = threadIdx.x, ty = threadIdx.y;  // 32 x 8
  for (int i = 0; i < 4; ++i)
    s[ty + i * 8][tx] = W[(r0 + ty + i * 8) * HID_ + k0 + tx];
  __syncthreads();
  for (int i = 0; i < 4; ++i)
    WT[(k0 + ty + i * 8) * G4_ + r0 + tx] = s[tx][ty + i * 8];
}

// ---------------- generic tiled f32 GEMM: C[M,N] = A[M,K] @ B[N,K]^T (+bias1[n]+bias2[n])
// requires M%64==0, N%64==0, K%32==0. block=256, grid=(N/64, M/64)
__global__ void k_gemm_bt(const float* __restrict__ A, const float* __restrict__ Bm,
                          const float* __restrict__ bias1, const float* __restrict__ bias2,
                          float* __restrict__ C, int M, int N, int K) {
  __shared__ float As[32][68];
  __shared__ float Bs[32][68];
  int tid = threadIdx.x;
  int tx = tid & 15, ty = tid >> 4;
  int n0 = blockIdx.x * 64, m0 = blockIdx.y * 64;
  float acc[4][4] = {};
  for (int k0 = 0; k0 < K; k0 += 32) {
    #pragma unroll
    for (int rep = 0; rep < 2; ++rep) {
      int idx = rep * 256 + tid;          // [0,512)
      int row = idx >> 3, kq = (idx & 7) * 4;
      float4 a4 = *(const float4*)&A[(m0 + row) * K + k0 + kq];
      As[kq + 0][row] = a4.x; As[kq + 1][row] = a4.y;
      As[kq + 2][row] = a4.z; As[kq + 3][row] = a4.w;
      float4 b4 = *(const float4*)&Bm[(n0 + row) * K + k0 + kq];
      Bs[kq + 0][row] = b4.x; Bs[kq + 1][row] = b4.y;
      Bs[kq + 2][row] = b4.z; Bs[kq + 3][row] = b4.w;
    }
    __syncthreads();
    #pragma unroll
    for (int k = 0; k < 32; ++k) {
      float4 a4 = *(const float4*)&As[k][ty * 4];
      float4 b4 = *(const float4*)&Bs[k][tx * 4];
      float av[4] = {a4.x, a4.y, a4.z, a4.w};
      float bv[4] = {b4.x, b4.y, b4.z, b4.w};
      #pragma unroll
      for (int i = 0; i < 4; ++i)
        #pragma unroll
        for (int j = 0; j < 4; ++j)
          acc[i][j] += av[i] * bv[j];
    }
    __syncthreads();
  }
  int nn = n0 + tx * 4;
  float bb[4] = {0.f, 0.f, 0.f, 0.f};
  if (bias1) {
    #pragma unroll
    for (int j = 0; j < 4; ++j) bb[j] += bias1[nn + j];
  }
  if (bias2) {
    #pragma unroll
    for (int j = 0; j < 4; ++j) bb[j] += bias2[nn + j];
  }
  #pragma unroll
  for (int i = 0; i < 4; ++i) {
    int m = m0 + ty * 4 + i;
    float4 o;
    o.x = acc[i][0] + bb[0]; o.y = acc[i][1] + bb[1];
    o.z = acc[i][2] + bb[2]; o.w = acc[i][3] + bb[3];
    *(float4*)&C[m * N + nn] = o;
  }
}

// ---------------- kernel: LSTM, one workgroup (1024 thr) per batch element
__global__ __launch_bounds__(1024) void k_lstm(const float* __restrict__ Xg,
                                               const float* __restrict__ WT,  // [512][2048]
                                               float* __restrict__ hs) {      // [1024][512]
  __shared__ float h_s[HID_];
  __shared__ float g_s[G4_];
  int b = blockIdx.x;
  int tid = threadIdx.x;
  int p = tid >> 9, u = tid & 511;
  int r = p * 1024 + u * 2;           // this thread computes gate rows r, r+1
  float c = 0.0f;
  if (tid < HID_) h_s[tid] = 0.0f;
  __syncthreads();
  for (int t = 0; t < T_; ++t) {
    int n = t * B_ + b;
    float2 acc = *(const float2*)&Xg[n * G4_ + r];
    for (int k4 = 0; k4 < HID_; k4 += 4) {
      float4 h4 = *(const float4*)&h_s[k4];
      float2 w;
      w = *(const float2*)&WT[(k4 + 0) * G4_ + r]; acc.x += h4.x * w.x; acc.y += h4.x * w.y;
      w = *(const float2*)&WT[(k4 + 1) * G4_ + r]; acc.x += h4.y * w.x; acc.y += h4.y * w.y;
      w = *(const float2*)&WT[(k4 + 2) * G4_ + r]; acc.x += h4.z * w.x; acc.y += h4.z * w.y;
      w = *(const float2*)&WT[(k4 + 3) * G4_ + r]; acc.x += h4.w * w.x; acc.y += h4.w * w.y;
    }
    *(float2*)&g_s[r] = acc;
    __syncthreads();
    if (tid < HID_) {
      int j = tid;
      float gi = sigmoidf_(g_s[j]);
      float gf = sigmoidf_(g_s[HID_ + j]);
      float gg = tanhf(g_s[2 * HID_ + j]);
      float go = sigmoidf_(g_s[3 * HID_ + j]);
      c = gf * c + gi * gg;
      float hn = go * tanhf(c);
      h_s[j] = hn;
      hs[n * HID_ + j] = hn;
    }
    __syncthreads();
  }
}

// ---------------- kernel: attention per (t,b): softmax(masked scores), p_gen, alpha
__global__ void k_attn(const float* __restrict__ hs, const float* __restrict__ q_ws,
                       const float* __restrict__ enc_out, const int* __restrict__ enc_in,
                       const float* __restrict__ pge_W, const float* __restrict__ pge_b,
                       const float* __restrict__ pgd_W, const float* __restrict__ pgd_b,
                       float* __restrict__ alpha, float* __restrict__ pgen) {
  __shared__ float h_s[HID_], q_s[EMB_], aw_s[L_], al_s[96], red_s[256];
  int n = blockIdx.x, tid = threadIdx.x;   // 1024 blocks x 256 threads
  int b = n & 31;
  h_s[tid]       = hs[n * HID_ + tid];
  h_s[tid + 256] = hs[n * HID_ + 256 + tid];
  q_s[tid]       = q_ws[n * EMB_ + tid];
  if (tid < 96) al_s[tid] = 0.0f;
  __syncthreads();
  // scores[l] = q . enc_out[b,l,:]; 4 partial lanes per l
  {
    int l = tid >> 2, part = tid & 3;
    const float* er = enc_out + (size_t)(b * L_ + l) * EMB_ + part * 64;
    const float* qp = q_s + part * 64;
    float acc = 0.f;
    #pragma unroll 8
    for (int i = 0; i < 64; ++i) acc += qp[i] * er[i];
    red_s[tid] = acc;
  }
  __syncthreads();
  if (tid < 64) {   // wave 0: reduce, mask, softmax across 64 lanes
    float s = red_s[tid * 4] + red_s[tid * 4 + 1] + red_s[tid * 4 + 2] + red_s[tid * 4 + 3];
    if (enc_in[b * L_ + tid] == 0) s = -1e30f;
    float m = s;
    for (int off = 32; off >= 1; off >>= 1) m = fmaxf(m, __shfl_xor(m, off));
    float e = expf(s - m);
    float sum = e;
    for (int off = 32; off >= 1; off >>= 1) sum += __shfl_xor(sum, off);
    aw_s[tid] = e / sum;
  }
  __syncthreads();
  // ctx[e] + p_gen partial
  float cacc = 0.f;
  for (int l2 = 0; l2 < L_; ++l2)
    cacc += aw_s[l2] * enc_out[(size_t)(b * L_ + l2) * EMB_ + tid];
  red_s[tid] = cacc * pge_W[tid] + h_s[tid] * pgd_W[tid] + h_s[tid + 256] * pgd_W[tid + 256];
  __syncthreads();
  for (int s2 = 128; s2 >= 1; s2 >>= 1) {
    if (tid < s2) red_s[tid] += red_s[tid + s2];
    __syncthreads();
  }
  if (tid == 0) pgen[n] = 1.0f / (1.0f + expf(-(red_s[0] + pge_b[0] + pgd_b[0])));
  // alpha[j] = sum of aw over slots with enc_in==j  (aw==0 at masked slots)
  if (tid < 64) atomicAdd(&al_s[enc_in[b * L_ + tid]], aw_s[tid]);
  __syncthreads();
  if (tid < 96) alpha[n * 96 + tid] = al_s[tid];
}

// ---------------- kernel: output = pg*(h@linW^T + lb) + (1-pg)*(alpha@converter)
// grid (469, 16), block 256; 64x64 tiles, per-thread 4x4
__global__ void k_out(const float* __restrict__ hs, const float* __restrict__ linW,
                      const float* __restrict__ linb, const float* __restrict__ conv,
                      const float* __restrict__ alpha, const float* __restrict__ pgen,
                      float* __restrict__ out) {
  __shared__ float As[32][68];
  __shared__ float Bs[32][68];
  __shared__ float alS[64 * 97];
  __shared__ float pg_s[64];
  int tid = threadIdx.x;
  int tx = tid & 15, ty = tid >> 4;
  int v0 = blockIdx.x * 64, n0 = blockIdx.y * 64;
  if (tid < 64) pg_s[tid] = pgen[n0 + tid];
  #pragma unroll
  for (int rep = 0; rep < 24; ++rep) {    // stage alpha 64x96 -> alS[row*97+j]
    int idx = rep * 256 + tid;
    int row = idx / 96, jj = idx - row * 96;
    alS[row * 97 + jj] = alpha[(n0 + row) * 96 + jj];
  }
  float acc1[4][4] = {};
  float acc2[4][4] = {};
  for (int k0 = 0; k0 < HID_; k0 += 32) {
    #pragma unroll
    for (int rep = 0; rep < 2; ++rep) {
      int idx = rep * 256 + tid;
      int row = idx >> 3, kq = (idx & 7) * 4;
      float4 a4 = *(const float4*)&hs[(n0 + row) * HID_ + k0 + kq];
      As[kq + 0][row] = a4.x; As[kq + 1][row] = a4.y;
      As[kq + 2][row] = a4.z; As[kq + 3][row] = a4.w;
      int vv = v0 + row; if (vv > V_ - 1) vv = V_ - 1;
      float4 b4 = *(const float4*)&linW[(size_t)vv * HID_ + k0 + kq];
      Bs[kq + 0][row] = b4.x; Bs[kq + 1][row] = b4.y;
      Bs[kq + 2][row] = b4.z; Bs[kq + 3][row] = b4.w;
    }
    __syncthreads();
    #pragma unroll
    for (int k = 0; k < 32; ++k) {
      float4 a4 = *(const float4*)&As[k][ty * 4];
      float4 b4 = *(const float4*)&Bs[k][tx * 4];
      float av[4] = {a4.x, a4.y, a4.z, a4.w};
      float bv[4] = {b4.x, b4.y, b4.z, b4.w};
      #pragma unroll
      for (int i = 0; i < 4; ++i)
        #pragma unroll
        for (int j = 0; j < 4; ++j)
          acc1[i][j] += av[i] * bv[j];
    }
    __syncthreads();
  }
  // pointer part: acc2 += alpha[row][j] * conv[j][v]
  int vq = v0 + tx * 4;
  int vc = vq > V_ - 4 ? V_ - 4 : vq;
  for (int j = 0; j < NOBJ_; ++j) {
    float4 c4 = *(const float4*)&conv[(size_t)j * V_ + vc];
    float cv[4] = {c4.x, c4.y, c4.z, c4.w};
    #pragma unroll
    for (int i = 0; i < 4; ++i) {
      float av = alS[(ty * 4 + i) * 97 + j];
      #pragma unroll
      for (int jj = 0; jj < 4; ++jj) acc2[i][jj] += av * cv[jj];
    }
  }
  if (vq + 3 < V_) {     // quads are fully in- or out-of-range (30000 % 4 == 0)
    float4 lb4 = *(const float4*)&linb[vq];
    float lb[4] = {lb4.x, lb4.y, lb4.z, lb4.w};
    #pragma unroll
    for (int i = 0; i < 4; ++i) {
      int row = ty * 4 + i;
      float pg = pg_s[row];
      float4 o;
      o.x = pg * (acc1[i][0] + lb[0]) + (1.0f - pg) * acc2[i][0];
      o.y = pg * (acc1[i][1] + lb[1]) + (1.0f - pg) * acc2[i][1];
      o.z = pg * (acc1[i][2] + lb[2]) + (1.0f - pg) * acc2[i][2];
      o.w = pg * (acc1[i][3] + lb[3]) + (1.0f - pg) * acc2[i][3];
      *(float4*)&out[(size_t)(n0 + row) * V_ + vq] = o;
    }
  }
}

extern "C" void kernel_launch(void* const* d_in, const int* in_sizes, int n_in,
                              void* d_out, int out_size, void* d_ws, size_t ws_size,
                              hipStream_t stream) {
  const float* features = (const float*)d_in[0];
  const int*   captions = (const int*)d_in[1];
  const int*   enc_in   = (const int*)d_in[3];
  const float* enc_out  = (const float*)d_in[4];
  const float* embed_W  = (const float*)d_in[5];
  const float* W_ih     = (const float*)d_in[6];
  const float* W_hh     = (const float*)d_in[7];
  const float* b_ih     = (const float*)d_in[8];
  const float* b_hh     = (const float*)d_in[9];
  const float* linear_W = (const float*)d_in[10];
  const float* linear_b = (const float*)d_in[11];
  const float* attn_W   = (const float*)d_in[12];
  const float* attn_b   = (const float*)d_in[13];
  const float* pge_W    = (const float*)d_in[14];
  const float* pge_b    = (const float*)d_in[15];
  const float* pgd_W    = (const float*)d_in[16];
  const float* pgd_b    = (const float*)d_in[17];
  const float* conv     = (const float*)d_in[18];
  float* out = (float*)d_out;

  float* ws  = (float*)d_ws;
  float* X   = ws;                 // 1024*256
  float* Xg  = X   + 262144;       // 1024*2048
  float* WT  = Xg  + 2097152;      // 512*2048
  float* hsb = WT  + 1048576;      // 1024*512
  float* qws = hsb + 524288;       // 1024*256
  float* alp = qws + 262144;       // 1024*96
  float* pgn = alp + 98304;        // 1024

  k_gather   <<<1024, 256, 0, stream>>>(features, captions, embed_W, X);
  k_transpose<<<dim3(16, 64), dim3(32, 8), 0, stream>>>(W_hh, WT);
  k_gemm_bt  <<<dim3(32, 16), 256, 0, stream>>>(X, W_ih, b_ih, b_hh, Xg, NROWS, G4_, EMB_);
  k_lstm     <<<32, 1024, 0, stream>>>(Xg, WT, hsb);
  k_gemm_bt  <<<dim3(4, 16), 256, 0, stream>>>(hsb, attn_W, attn_b, nullptr, qws, NROWS, EMB_, HID_);
  k_attn     <<<1024, 256, 0, stream>>>(hsb, qws, enc_out, enc_in, pge_W, pge_b, pgd_W, pgd_b, alp, pgn);
  k_out      <<<dim3(469, 16), 256, 0, stream>>>(hsb, linear_W, linear_b, conv, alp, pgn, out);
}

// Round 2
// 1922.252 us; speedup vs baseline: 1.3838x; 1.3838x over previous
//
#include <hip/hip_runtime.h>
#include <hip/hip_bf16.h>
#include <hip/hip_cooperative_groups.h>
#include <math.h>

namespace cg = cooperative_groups;

#define B_    32
#define T_    32
#define L_    64
#define EMB_  256
#define HID_  512
#define G4_   2048   // 4*HID
#define V_    30000
#define NOBJ_ 91
#define NROWS 1024   // T_*B_

__device__ __forceinline__ float sigmoidf_(float x) { return 1.0f / (1.0f + expf(-x)); }

// ---------------- kernel 1: gather embeddings, time-major X[n][256], n = t*32+b
__global__ void k_gather(const float* __restrict__ features,
                         const int*   __restrict__ captions,
                         const float* __restrict__ embed_W,
                         float* __restrict__ X) {
  int n = blockIdx.x, e = threadIdx.x;          // 1024 blocks x 256 threads
  int t = n >> 5, b = n & 31;
  float v;
  if (t == 0) v = features[b * EMB_ + e];
  else        v = embed_W[captions[b * T_ + (t - 1)] * EMB_ + e];
  X[n * EMB_ + e] = v;
}

// ---------------- generic tiled f32 GEMM: C[M,N] = A[M,K] @ B[N,K]^T (+bias1[n]+bias2[n])
__global__ void k_gemm_bt(const float* __restrict__ A, const float* __restrict__ Bm,
                          const float* __restrict__ bias1, const float* __restrict__ bias2,
                          float* __restrict__ C, int M, int N, int K) {
  __shared__ float As[32][68];
  __shared__ float Bs[32][68];
  int tid = threadIdx.x;
  int tx = tid & 15, ty = tid >> 4;
  int n0 = blockIdx.x * 64, m0 = blockIdx.y * 64;
  float acc[4][4] = {};
  for (int k0 = 0; k0 < K; k0 += 32) {
    #pragma unroll
    for (int rep = 0; rep < 2; ++rep) {
      int idx = rep * 256 + tid;          // [0,512)
      int row = idx >> 3, kq = (idx & 7) * 4;
      float4 a4 = *(const float4*)&A[(m0 + row) * K + k0 + kq];
      As[kq + 0][row] = a4.x; As[kq + 1][row] = a4.y;
      As[kq + 2][row] = a4.z; As[kq + 3][row] = a4.w;
      float4 b4 = *(const float4*)&Bm[(n0 + row) * K + k0 + kq];
      Bs[kq + 0][row] = b4.x; Bs[kq + 1][row] = b4.y;
      Bs[kq + 2][row] = b4.z; Bs[kq + 3][row] = b4.w;
    }
    __syncthreads();
    #pragma unroll
    for (int k = 0; k < 32; ++k) {
      float4 a4 = *(const float4*)&As[k][ty * 4];
      float4 b4 = *(const float4*)&Bs[k][tx * 4];
      float av[4] = {a4.x, a4.y, a4.z, a4.w};
      float bv[4] = {b4.x, b4.y, b4.z, b4.w};
      #pragma unroll
      for (int i = 0; i < 4; ++i)
        #pragma unroll
        for (int j = 0; j < 4; ++j)
          acc[i][j] += av[i] * bv[j];
    }
    __syncthreads();
  }
  int nn = n0 + tx * 4;
  float bb[4] = {0.f, 0.f, 0.f, 0.f};
  if (bias1) {
    #pragma unroll
    for (int j = 0; j < 4; ++j) bb[j] += bias1[nn + j];
  }
  if (bias2) {
    #pragma unroll
    for (int j = 0; j < 4; ++j) bb[j] += bias2[nn + j];
  }
  #pragma unroll
  for (int i = 0; i < 4; ++i) {
    int m = m0 + ty * 4 + i;
    float4 o;
    o.x = acc[i][0] + bb[0]; o.y = acc[i][1] + bb[1];
    o.z = acc[i][2] + bb[2]; o.w = acc[i][3] + bb[3];
    *(float4*)&C[m * N + nn] = o;
  }
}

// ---------------- cooperative persistent LSTM
// grid 256 x block 256. Block m owns h-dims j in {2m, 2m+1}: 8 gate rows
// (local row q = gate*2 + jj  <->  global row gate*512 + 2m + jj).
// Weight slice (8x512, 16 KB) lives in LDS for the whole kernel.
// Per timestep: h read from global hT[cur] [512][32] (L2-hot, shared),
// 4b x 4r micro-tile, k split 16 ways (4 in-wave via shfl + 4 across waves
// via LDS), then 64 threads do gates + c/h update and write hT[next].
// One grid.sync per timestep; hT double-buffered so step t+1 writes never
// collide with step t reads.
__global__ __launch_bounds__(256) void k_lstm_coop(
    const float* __restrict__ Xg,    // [1024][2048] input gates (time-major)
    const float* __restrict__ W_hh,  // [2048][512]
    float* __restrict__ hTbuf,       // [2][512][32]
    float* __restrict__ hs) {        // [1024][512]
  __shared__ float wt_s[512 * 8];        // [k][q], 16 KB
  __shared__ float gredw[4 * 8 * 32];    // [wave][q][b], 4 KB
  cg::grid_group grid = cg::this_grid();
  const int m = blockIdx.x;
  const int j0 = 2 * m;
  const int tid = threadIdx.x;
  // thread coords: tid = kc*16 + rg*8 + bg
  const int kc = tid >> 4;          // [0,16) k-chunk (interleaved k = kk*16+kc)
  const int rg = (tid >> 3) & 1;    // [0,2)  row half (rows rg*4 .. rg*4+3)
  const int bg = tid & 7;           // [0,8)  b quad (b = 4*bg .. 4*bg+3)
  const int jj = tid >> 5, bb = tid & 31;   // phase-D coords (tid < 64)

  // stage weight slice once: wt_s[k*8 + q] = W_hh[(q>>1)*512 + j0 + (q&1)][k]
  {
    int q = tid >> 5, lane = tid & 31;
    const float* src = W_hh + (size_t)((q >> 1) * 512 + j0 + (q & 1)) * HID_;
    for (int kk = 0; kk < 16; ++kk) {
      int k = kk * 32 + lane;
      wt_s[k * 8 + q] = src[k];
    }
  }
  __syncthreads();

  float c = 0.0f;
  for (int t = 0; t < T_; ++t) {
    const float* hTcur = hTbuf + (t & 1) * (HID_ * B_);
    float* hTnext      = hTbuf + ((t + 1) & 1) * (HID_ * B_);
    // prefetch input-gate contributions (consumed in phase D)
    float xg0 = 0.f, xg1 = 0.f, xg2 = 0.f, xg3 = 0.f;
    if (tid < 64) {
      const float* xp = Xg + (size_t)(t * B_ + bb) * G4_ + j0 + jj;
      xg0 = xp[0]; xg1 = xp[512]; xg2 = xp[1024]; xg3 = xp[1536];
    }
    // phase B: partial GEMM. acc[j][i]: row rg*4+j, batch 4*bg+i, k = kk*16+kc
    float acc[4][4] = {};
    if (t > 0) {
      #pragma unroll 4
      for (int kk = 0; kk < 32; ++kk) {
        float4 h4 = *(const float4*)&hTcur[kk * 512 + kc * 32 + 4 * bg];
        float4 w4 = *(const float4*)&wt_s[(kk * 16 + kc) * 8 + 4 * rg];
        acc[0][0] += w4.x * h4.x; acc[0][1] += w4.x * h4.y; acc[0][2] += w4.x * h4.z; acc[0][3] += w4.x * h4.w;
        acc[1][0] += w4.y * h4.x; acc[1][1] += w4.y * h4.y; acc[1][2] += w4.y * h4.z; acc[1][3] += w4.y * h4.w;
        acc[2][0] += w4.z * h4.x; acc[2][1] += w4.z * h4.y; acc[2][2] += w4.z * h4.z; acc[2][3] += w4.z * h4.w;
        acc[3][0] += w4.w * h4.x; acc[3][1] += w4.w * h4.y; acc[3][2] += w4.w * h4.z; acc[3][3] += w4.w * h4.w;
      }
    }
    // phase C: reduce the 4 in-wave k-chunks (lanes differ in bits 4..5)
    #pragma unroll
    for (int j = 0; j < 4; ++j)
      #pragma unroll
      for (int i = 0; i < 4; ++i) {
        acc[j][i] += __shfl_xor(acc[j][i], 16);
        acc[j][i] += __shfl_xor(acc[j][i], 32);
      }
    if ((tid & 63) < 16) {
      int w = tid >> 6;
      #pragma unroll
      for (int j = 0; j < 4; ++j) {
        float4 v; v.x = acc[j][0]; v.y = acc[j][1]; v.z = acc[j][2]; v.w = acc[j][3];
        *(float4*)&gredw[w * 256 + (rg * 4 + j) * 32 + bg * 4] = v;
      }
    }
    __syncthreads();
    // phase D: gates + state update (64 threads: jj in {0,1}, bb in [0,32))
    if (tid < 64) {
      float s0 = xg0, s1 = xg1, s2 = xg2, s3 = xg3;
      #pragma unroll
      for (int w = 0; w < 4; ++w) {
        s0 += gredw[w * 256 + (0 * 2 + jj) * 32 + bb];
        s1 += gredw[w * 256 + (1 * 2 + jj) * 32 + bb];
        s2 += gredw[w * 256 + (2 * 2 + jj) * 32 + bb];
        s3 += gredw[w * 256 + (3 * 2 + jj) * 32 + bb];
      }
      float gi = sigmoidf_(s0), gf = sigmoidf_(s1);
      float gg = tanhf(s2),     go = sigmoidf_(s3);
      c = gf * c + gi * gg;
      float h = go * tanhf(c);
      hTnext[(j0 + jj) * B_ + bb] = h;
      hs[(size_t)(t * B_ + bb) * HID_ + j0 + jj] = h;
    }
    grid.sync();
  }
}

// ---------------- kernel: attention per (t,b): softmax(masked scores), p_gen, alpha
__global__ void k_attn(const float* __restrict__ hs, const float* __restrict__ q_ws,
                       const float* __restrict__ enc_out, const int* __restrict__ enc_in,
                       const float* __restrict__ pge_W, const float* __restrict__ pge_b,
                       const float* __restrict__ pgd_W, const float* __restrict__ pgd_b,
                       float* __restrict__ alpha, float* __restrict__ pgen) {
  __shared__ float h_s[HID_], q_s[EMB_], aw_s[L_], al_s[96], red_s[256];
  int n = blockIdx.x, tid = threadIdx.x;   // 1024 blocks x 256 threads
  int b = n & 31;
  h_s[tid]       = hs[n * HID_ + tid];
  h_s[tid + 256] = hs[n * HID_ + 256 + tid];
  q_s[tid]       = q_ws[n * EMB_ + tid];
  if (tid < 96) al_s[tid] = 0.0f;
  __syncthreads();
  {
    int l = tid >> 2, part = tid & 3;
    const float* er = enc_out + (size_t)(b * L_ + l) * EMB_ + part * 64;
    const float* qp = q_s + part * 64;
    float acc = 0.f;
    #pragma unroll 8
    for (int i = 0; i < 64; ++i) acc += qp[i] * er[i];
    red_s[tid] = acc;
  }
  __syncthreads();
  if (tid < 64) {
    float s = red_s[tid * 4] + red_s[tid * 4 + 1] + red_s[tid * 4 + 2] + red_s[tid * 4 + 3];
    if (enc_in[b * L_ + tid] == 0) s = -1e30f;
    float mx = s;
    for (int off = 32; off >= 1; off >>= 1) mx = fmaxf(mx, __shfl_xor(mx, off));
    float e = expf(s - mx);
    float sum = e;
    for (int off = 32; off >= 1; off >>= 1) sum += __shfl_xor(sum, off);
    aw_s[tid] = e / sum;
  }
  __syncthreads();
  float cacc = 0.f;
  for (int l2 = 0; l2 < L_; ++l2)
    cacc += aw_s[l2] * enc_out[(size_t)(b * L_ + l2) * EMB_ + tid];
  red_s[tid] = cacc * pge_W[tid] + h_s[tid] * pgd_W[tid] + h_s[tid + 256] * pgd_W[tid + 256];
  __syncthreads();
  for (int s2 = 128; s2 >= 1; s2 >>= 1) {
    if (tid < s2) red_s[tid] += red_s[tid + s2];
    __syncthreads();
  }
  if (tid == 0) pgen[n] = 1.0f / (1.0f + expf(-(red_s[0] + pge_b[0] + pgd_b[0])));
  if (tid < 64) atomicAdd(&al_s[enc_in[b * L_ + tid]], aw_s[tid]);
  __syncthreads();
  if (tid < 96) alpha[n * 96 + tid] = al_s[tid];
}

// ---------------- kernel: output = pg*(h@linW^T + lb) + (1-pg)*(alpha@converter)
__global__ void k_out(const float* __restrict__ hs, const float* __restrict__ linW,
                      const float* __restrict__ linb, const float* __restrict__ conv,
                      const float* __restrict__ alpha, const float* __restrict__ pgen,
                      float* __restrict__ out) {
  __shared__ float As[32][68];
  __shared__ float Bs[32][68];
  __shared__ float alS[64 * 97];
  __shared__ float pg_s[64];
  int tid = threadIdx.x;
  int tx = tid & 15, ty = tid >> 4;
  int v0 = blockIdx.x * 64, n0 = blockIdx.y * 64;
  if (tid < 64) pg_s[tid] = pgen[n0 + tid];
  #pragma unroll
  for (int rep = 0; rep < 24; ++rep) {
    int idx = rep * 256 + tid;
    int row = idx / 96, jjx = idx - row * 96;
    alS[row * 97 + jjx] = alpha[(n0 + row) * 96 + jjx];
  }
  float acc1[4][4] = {};
  float acc2[4][4] = {};
  for (int k0 = 0; k0 < HID_; k0 += 32) {
    #pragma unroll
    for (int rep = 0; rep < 2; ++rep) {
      int idx = rep * 256 + tid;
      int row = idx >> 3, kq = (idx & 7) * 4;
      float4 a4 = *(const float4*)&hs[(n0 + row) * HID_ + k0 + kq];
      As[kq + 0][row] = a4.x; As[kq + 1][row] = a4.y;
      As[kq + 2][row] = a4.z; As[kq + 3][row] = a4.w;
      int vv = v0 + row; if (vv > V_ - 1) vv = V_ - 1;
      float4 b4 = *(const float4*)&linW[(size_t)vv * HID_ + k0 + kq];
      Bs[kq + 0][row] = b4.x; Bs[kq + 1][row] = b4.y;
      Bs[kq + 2][row] = b4.z; Bs[kq + 3][row] = b4.w;
    }
    __syncthreads();
    #pragma unroll
    for (int k = 0; k < 32; ++k) {
      float4 a4 = *(const float4*)&As[k][ty * 4];
      float4 b4 = *(const float4*)&Bs[k][tx * 4];
      float av[4] = {a4.x, a4.y, a4.z, a4.w};
      float bv[4] = {b4.x, b4.y, b4.z, b4.w};
      #pragma unroll
      for (int i = 0; i < 4; ++i)
        #pragma unroll
        for (int j = 0; j < 4; ++j)
          acc1[i][j] += av[i] * bv[j];
    }
    __syncthreads();
  }
  int vq = v0 + tx * 4;
  int vc = vq > V_ - 4 ? V_ - 4 : vq;
  for (int j = 0; j < NOBJ_; ++j) {
    float4 c4 = *(const float4*)&conv[(size_t)j * V_ + vc];
    float cv[4] = {c4.x, c4.y, c4.z, c4.w};
    #pragma unroll
    for (int i = 0; i < 4; ++i) {
      float av = alS[(ty * 4 + i) * 97 + j];
      #pragma unroll
      for (int jjx = 0; jjx < 4; ++jjx) acc2[i][jjx] += av * cv[jjx];
    }
  }
  if (vq + 3 < V_) {
    float4 lb4 = *(const float4*)&linb[vq];
    float lb[4] = {lb4.x, lb4.y, lb4.z, lb4.w};
    #pragma unroll
    for (int i = 0; i < 4; ++i) {
      int row = ty * 4 + i;
      float pg = pg_s[row];
      float4 o;
      o.x = pg * (acc1[i][0] + lb[0]) + (1.0f - pg) * acc2[i][0];
      o.y = pg * (acc1[i][1] + lb[1]) + (1.0f - pg) * acc2[i][1];
      o.z = pg * (acc1[i][2] + lb[2]) + (1.0f - pg) * acc2[i][2];
      o.w = pg * (acc1[i][3] + lb[3]) + (1.0f - pg) * acc2[i][3];
      *(float4*)&out[(size_t)(n0 + row) * V_ + vq] = o;
    }
  }
}

extern "C" void kernel_launch(void* const* d_in, const int* in_sizes, int n_in,
                              void* d_out, int out_size, void* d_ws, size_t ws_size,
                              hipStream_t stream) {
  const float* features = (const float*)d_in[0];
  const int*   captions = (const int*)d_in[1];
  const int*   enc_in   = (const int*)d_in[3];
  const float* enc_out  = (const float*)d_in[4];
  const float* embed_W  = (const float*)d_in[5];
  const float* W_ih     = (const float*)d_in[6];
  const float* W_hh     = (const float*)d_in[7];
  const float* b_ih     = (const float*)d_in[8];
  const float* b_hh     = (const float*)d_in[9];
  const float* linear_W = (const float*)d_in[10];
  const float* linear_b = (const float*)d_in[11];
  const float* attn_W   = (const float*)d_in[12];
  const float* attn_b   = (const float*)d_in[13];
  const float* pge_W    = (const float*)d_in[14];
  const float* pge_b    = (const float*)d_in[15];
  const float* pgd_W    = (const float*)d_in[16];
  const float* pgd_b    = (const float*)d_in[17];
  const float* conv     = (const float*)d_in[18];
  float* out = (float*)d_out;

  float* ws   = (float*)d_ws;
  float* X    = ws;                  // 1024*256
  float* Xg   = X    + 262144;       // 1024*2048
  float* hTb  = Xg   + 2097152;      // 2*512*32
  float* hsb  = hTb  + 32768;        // 1024*512
  float* qws  = hsb  + 524288;       // 1024*256
  float* alp  = qws  + 262144;       // 1024*96
  float* pgn  = alp  + 98304;        // 1024

  k_gather <<<1024, 256, 0, stream>>>(features, captions, embed_W, X);
  k_gemm_bt<<<dim3(32, 16), 256, 0, stream>>>(X, W_ih, b_ih, b_hh, Xg, NROWS, G4_, EMB_);
  {
    const float* Xg_c = Xg;
    const float* Whh_c = W_hh;
    float* hTb_p = hTb;
    float* hsb_p = hsb;
    void* args[] = { (void*)&Xg_c, (void*)&Whh_c, (void*)&hTb_p, (void*)&hsb_p };
    hipLaunchCooperativeKernel((const void*)k_lstm_coop, dim3(256), dim3(256),
                               args, 0, stream);
  }
  k_gemm_bt<<<dim3(4, 16), 256, 0, stream>>>(hsb, attn_W, attn_b, nullptr, qws, NROWS, EMB_, HID_);
  k_attn   <<<1024, 256, 0, stream>>>(hsb, qws, enc_out, enc_in, pge_W, pge_b, pgd_W, pgd_b, alp, pgn);
  k_out    <<<dim3(469, 16), 256, 0, stream>>>(hsb, linear_W, linear_b, conv, alp, pgn, out);
}

// Round 3
// 1738.916 us; speedup vs baseline: 1.5296x; 1.1054x over previous
//
#include <hip/hip_runtime.h>
#include <hip/hip_bf16.h>
#include <math.h>

#define B_    32
#define T_    32
#define L_    64
#define EMB_  256
#define HID_  512
#define G4_   2048   // 4*HID
#define V_    30000
#define NOBJ_ 91
#define NROWS 1024   // T_*B_

__device__ __forceinline__ float sigmoidf_(float x) { return 1.0f / (1.0f + expf(-x)); }

// Lean agent-scope grid barrier (cg::grid.sync uses system scope = ~33us/step).
// Sense-reversing via generation counter; thread 0 arrives/spins, block waits
// at __syncthreads. ACQ_REL/ACQUIRE at AGENT scope give cross-XCD visibility
// of the plain hT stores (compiler emits buffer_wbl2/buffer_inv sc1).
__device__ __forceinline__ void grid_barrier(unsigned* cnt, unsigned* gen, unsigned nblocks) {
  __syncthreads();
  if (threadIdx.x == 0) {
    unsigned g = __hip_atomic_load(gen, __ATOMIC_RELAXED, __HIP_MEMORY_SCOPE_AGENT);
    unsigned arrived = __hip_atomic_fetch_add(cnt, 1u, __ATOMIC_ACQ_REL, __HIP_MEMORY_SCOPE_AGENT) + 1u;
    if (arrived == nblocks) {
      __hip_atomic_store(cnt, 0u, __ATOMIC_RELAXED, __HIP_MEMORY_SCOPE_AGENT);
      __hip_atomic_store(gen, g + 1u, __ATOMIC_RELEASE, __HIP_MEMORY_SCOPE_AGENT);
    } else {
      unsigned cur;
      do {
        __builtin_amdgcn_s_sleep(1);
        cur = __hip_atomic_load(gen, __ATOMIC_ACQUIRE, __HIP_MEMORY_SCOPE_AGENT);
      } while (cur == g);
    }
  }
  __syncthreads();
}

// ---------------- kernel 1: gather embeddings, time-major X[n][256], n = t*32+b
__global__ void k_gather(const float* __restrict__ features,
                         const int*   __restrict__ captions,
                         const float* __restrict__ embed_W,
                         float* __restrict__ X) {
  int n = blockIdx.x, e = threadIdx.x;          // 1024 blocks x 256 threads
  int t = n >> 5, b = n & 31;
  float v;
  if (t == 0) v = features[b * EMB_ + e];
  else        v = embed_W[captions[b * T_ + (t - 1)] * EMB_ + e];
  X[n * EMB_ + e] = v;
}

// ---------------- generic tiled f32 GEMM: C[M,N] = A[M,K] @ B[N,K]^T (+bias1[n]+bias2[n])
__global__ void k_gemm_bt(const float* __restrict__ A, const float* __restrict__ Bm,
                          const float* __restrict__ bias1, const float* __restrict__ bias2,
                          float* __restrict__ C, int M, int N, int K) {
  __shared__ float As[32][68];
  __shared__ float Bs[32][68];
  int tid = threadIdx.x;
  int tx = tid & 15, ty = tid >> 4;
  int n0 = blockIdx.x * 64, m0 = blockIdx.y * 64;
  float acc[4][4] = {};
  for (int k0 = 0; k0 < K; k0 += 32) {
    #pragma unroll
    for (int rep = 0; rep < 2; ++rep) {
      int idx = rep * 256 + tid;          // [0,512)
      int row = idx >> 3, kq = (idx & 7) * 4;
      float4 a4 = *(const float4*)&A[(m0 + row) * K + k0 + kq];
      As[kq + 0][row] = a4.x; As[kq + 1][row] = a4.y;
      As[kq + 2][row] = a4.z; As[kq + 3][row] = a4.w;
      float4 b4 = *(const float4*)&Bm[(n0 + row) * K + k0 + kq];
      Bs[kq + 0][row] = b4.x; Bs[kq + 1][row] = b4.y;
      Bs[kq + 2][row] = b4.z; Bs[kq + 3][row] = b4.w;
    }
    __syncthreads();
    #pragma unroll
    for (int k = 0; k < 32; ++k) {
      float4 a4 = *(const float4*)&As[k][ty * 4];
      float4 b4 = *(const float4*)&Bs[k][tx * 4];
      float av[4] = {a4.x, a4.y, a4.z, a4.w};
      float bv[4] = {b4.x, b4.y, b4.z, b4.w};
      #pragma unroll
      for (int i = 0; i < 4; ++i)
        #pragma unroll
        for (int j = 0; j < 4; ++j)
          acc[i][j] += av[i] * bv[j];
    }
    __syncthreads();
  }
  int nn = n0 + tx * 4;
  float bb[4] = {0.f, 0.f, 0.f, 0.f};
  if (bias1) {
    #pragma unroll
    for (int j = 0; j < 4; ++j) bb[j] += bias1[nn + j];
  }
  if (bias2) {
    #pragma unroll
    for (int j = 0; j < 4; ++j) bb[j] += bias2[nn + j];
  }
  #pragma unroll
  for (int i = 0; i < 4; ++i) {
    int m = m0 + ty * 4 + i;
    float4 o;
    o.x = acc[i][0] + bb[0]; o.y = acc[i][1] + bb[1];
    o.z = acc[i][2] + bb[2]; o.w = acc[i][3] + bb[3];
    *(float4*)&C[m * N + nn] = o;
  }
}

// ---------------- cooperative persistent LSTM (structure as round 2, but with
// the lean agent-scope barrier instead of cg::grid.sync)
__global__ __launch_bounds__(256) void k_lstm_coop(
    const float* __restrict__ Xg,    // [1024][2048] input gates (time-major)
    const float* __restrict__ W_hh,  // [2048][512]
    float* __restrict__ hTbuf,       // [2][512][32]
    float* __restrict__ hs,          // [1024][512]
    unsigned* __restrict__ bar_cnt,
    unsigned* __restrict__ bar_gen) {
  __shared__ float wt_s[512 * 8];        // [k][q], 16 KB
  __shared__ float gredw[4 * 8 * 32];    // [wave][q][b], 4 KB
  const int m = blockIdx.x;
  const int j0 = 2 * m;
  const int tid = threadIdx.x;
  const int kc = tid >> 4;          // [0,16) k-chunk (interleaved k = kk*16+kc)
  const int rg = (tid >> 3) & 1;    // [0,2)  row half (rows rg*4 .. rg*4+3)
  const int bg = tid & 7;           // [0,8)  b quad (b = 4*bg .. 4*bg+3)
  const int jj = tid >> 5, bb = tid & 31;   // phase-D coords (tid < 64)

  // stage weight slice once: wt_s[k*8 + q] = W_hh[(q>>1)*512 + j0 + (q&1)][k]
  {
    int q = tid >> 5, lane = tid & 31;
    const float* src = W_hh + (size_t)((q >> 1) * 512 + j0 + (q & 1)) * HID_;
    for (int kk = 0; kk < 16; ++kk) {
      int k = kk * 32 + lane;
      wt_s[k * 8 + q] = src[k];
    }
  }
  __syncthreads();

  float c = 0.0f;
  for (int t = 0; t < T_; ++t) {
    const float* hTcur = hTbuf + (t & 1) * (HID_ * B_);
    float* hTnext      = hTbuf + ((t + 1) & 1) * (HID_ * B_);
    float xg0 = 0.f, xg1 = 0.f, xg2 = 0.f, xg3 = 0.f;
    if (tid < 64) {
      const float* xp = Xg + (size_t)(t * B_ + bb) * G4_ + j0 + jj;
      xg0 = xp[0]; xg1 = xp[512]; xg2 = xp[1024]; xg3 = xp[1536];
    }
    // phase B: partial GEMM. acc[j][i]: row rg*4+j, batch 4*bg+i, k = kk*16+kc
    float acc[4][4] = {};
    if (t > 0) {
      #pragma unroll 4
      for (int kk = 0; kk < 32; ++kk) {
        float4 h4 = *(const float4*)&hTcur[kk * 512 + kc * 32 + 4 * bg];
        float4 w4 = *(const float4*)&wt_s[(kk * 16 + kc) * 8 + 4 * rg];
        acc[0][0] += w4.x * h4.x; acc[0][1] += w4.x * h4.y; acc[0][2] += w4.x * h4.z; acc[0][3] += w4.x * h4.w;
        acc[1][0] += w4.y * h4.x; acc[1][1] += w4.y * h4.y; acc[1][2] += w4.y * h4.z; acc[1][3] += w4.y * h4.w;
        acc[2][0] += w4.z * h4.x; acc[2][1] += w4.z * h4.y; acc[2][2] += w4.z * h4.z; acc[2][3] += w4.z * h4.w;
        acc[3][0] += w4.w * h4.x; acc[3][1] += w4.w * h4.y; acc[3][2] += w4.w * h4.z; acc[3][3] += w4.w * h4.w;
      }
    }
    // phase C: reduce the 4 in-wave k-chunks (lanes differ in bits 4..5)
    #pragma unroll
    for (int j = 0; j < 4; ++j)
      #pragma unroll
      for (int i = 0; i < 4; ++i) {
        acc[j][i] += __shfl_xor(acc[j][i], 16);
        acc[j][i] += __shfl_xor(acc[j][i], 32);
      }
    if ((tid & 63) < 16) {
      int w = tid >> 6;
      #pragma unroll
      for (int j = 0; j < 4; ++j) {
        float4 v; v.x = acc[j][0]; v.y = acc[j][1]; v.z = acc[j][2]; v.w = acc[j][3];
        *(float4*)&gredw[w * 256 + (rg * 4 + j) * 32 + bg * 4] = v;
      }
    }
    __syncthreads();
    // phase D: gates + state update (64 threads: jj in {0,1}, bb in [0,32))
    if (tid < 64) {
      float s0 = xg0, s1 = xg1, s2 = xg2, s3 = xg3;
      #pragma unroll
      for (int w = 0; w < 4; ++w) {
        s0 += gredw[w * 256 + (0 * 2 + jj) * 32 + bb];
        s1 += gredw[w * 256 + (1 * 2 + jj) * 32 + bb];
        s2 += gredw[w * 256 + (2 * 2 + jj) * 32 + bb];
        s3 += gredw[w * 256 + (3 * 2 + jj) * 32 + bb];
      }
      float gi = sigmoidf_(s0), gf = sigmoidf_(s1);
      float gg = tanhf(s2),     go = sigmoidf_(s3);
      c = gf * c + gi * gg;
      float h = go * tanhf(c);
      hTnext[(j0 + jj) * B_ + bb] = h;
      hs[(size_t)(t * B_ + bb) * HID_ + j0 + jj] = h;
    }
    grid_barrier(bar_cnt, bar_gen, 256u);
  }
}

// ---------------- kernel: attention per (t,b): softmax(masked scores), p_gen, alpha
__global__ void k_attn(const float* __restrict__ hs, const float* __restrict__ q_ws,
                       const float* __restrict__ enc_out, const int* __restrict__ enc_in,
                       const float* __restrict__ pge_W, const float* __restrict__ pge_b,
                       const float* __restrict__ pgd_W, const float* __restrict__ pgd_b,
                       float* __restrict__ alpha, float* __restrict__ pgen) {
  __shared__ float h_s[HID_], q_s[EMB_], aw_s[L_], al_s[96], red_s[256];
  int n = blockIdx.x, tid = threadIdx.x;   // 1024 blocks x 256 threads
  int b = n & 31;
  h_s[tid]       = hs[n * HID_ + tid];
  h_s[tid + 256] = hs[n * HID_ + 256 + tid];
  q_s[tid]       = q_ws[n * EMB_ + tid];
  if (tid < 96) al_s[tid] = 0.0f;
  __syncthreads();
  {
    int l = tid >> 2, part = tid & 3;
    const float* er = enc_out + (size_t)(b * L_ + l) * EMB_ + part * 64;
    const float* qp = q_s + part * 64;
    float acc = 0.f;
    #pragma unroll 8
    for (int i = 0; i < 64; ++i) acc += qp[i] * er[i];
    red_s[tid] = acc;
  }
  __syncthreads();
  if (tid < 64) {
    float s = red_s[tid * 4] + red_s[tid * 4 + 1] + red_s[tid * 4 + 2] + red_s[tid * 4 + 3];
    if (enc_in[b * L_ + tid] == 0) s = -1e30f;
    float mx = s;
    for (int off = 32; off >= 1; off >>= 1) mx = fmaxf(mx, __shfl_xor(mx, off));
    float e = expf(s - mx);
    float sum = e;
    for (int off = 32; off >= 1; off >>= 1) sum += __shfl_xor(sum, off);
    aw_s[tid] = e / sum;
  }
  __syncthreads();
  float cacc = 0.f;
  for (int l2 = 0; l2 < L_; ++l2)
    cacc += aw_s[l2] * enc_out[(size_t)(b * L_ + l2) * EMB_ + tid];
  red_s[tid] = cacc * pge_W[tid] + h_s[tid] * pgd_W[tid] + h_s[tid + 256] * pgd_W[tid + 256];
  __syncthreads();
  for (int s2 = 128; s2 >= 1; s2 >>= 1) {
    if (tid < s2) red_s[tid] += red_s[tid + s2];
    __syncthreads();
  }
  if (tid == 0) pgen[n] = 1.0f / (1.0f + expf(-(red_s[0] + pge_b[0] + pgd_b[0])));
  if (tid < 64) atomicAdd(&al_s[enc_in[b * L_ + tid]], aw_s[tid]);
  __syncthreads();
  if (tid < 96) alpha[n * 96 + tid] = al_s[tid];
}

// ---------------- kernel: output = pg*(h@linW^T + lb) + (1-pg)*(alpha@converter)
__global__ void k_out(const float* __restrict__ hs, const float* __restrict__ linW,
                      const float* __restrict__ linb, const float* __restrict__ conv,
                      const float* __restrict__ alpha, const float* __restrict__ pgen,
                      float* __restrict__ out) {
  __shared__ float As[32][68];
  __shared__ float Bs[32][68];
  __shared__ float alS[64 * 97];
  __shared__ float pg_s[64];
  int tid = threadIdx.x;
  int tx = tid & 15, ty = tid >> 4;
  int v0 = blockIdx.x * 64, n0 = blockIdx.y * 64;
  if (tid < 64) pg_s[tid] = pgen[n0 + tid];
  #pragma unroll
  for (int rep = 0; rep < 24; ++rep) {
    int idx = rep * 256 + tid;
    int row = idx / 96, jjx = idx - row * 96;
    alS[row * 97 + jjx] = alpha[(n0 + row) * 96 + jjx];
  }
  float acc1[4][4] = {};
  float acc2[4][4] = {};
  for (int k0 = 0; k0 < HID_; k0 += 32) {
    #pragma unroll
    for (int rep = 0; rep < 2; ++rep) {
      int idx = rep * 256 + tid;
      int row = idx >> 3, kq = (idx & 7) * 4;
      float4 a4 = *(const float4*)&hs[(n0 + row) * HID_ + k0 + kq];
      As[kq + 0][row] = a4.x; As[kq + 1][row] = a4.y;
      As[kq + 2][row] = a4.z; As[kq + 3][row] = a4.w;
      int vv = v0 + row; if (vv > V_ - 1) vv = V_ - 1;
      float4 b4 = *(const float4*)&linW[(size_t)vv * HID_ + k0 + kq];
      Bs[kq + 0][row] = b4.x; Bs[kq + 1][row] = b4.y;
      Bs[kq + 2][row] = b4.z; Bs[kq + 3][row] = b4.w;
    }
    __syncthreads();
    #pragma unroll
    for (int k = 0; k < 32; ++k) {
      float4 a4 = *(const float4*)&As[k][ty * 4];
      float4 b4 = *(const float4*)&Bs[k][tx * 4];
      float av[4] = {a4.x, a4.y, a4.z, a4.w};
      float bv[4] = {b4.x, b4.y, b4.z, b4.w};
      #pragma unroll
      for (int i = 0; i < 4; ++i)
        #pragma unroll
        for (int j = 0; j < 4; ++j)
          acc1[i][j] += av[i] * bv[j];
    }
    __syncthreads();
  }
  int vq = v0 + tx * 4;
  int vc = vq > V_ - 4 ? V_ - 4 : vq;
  for (int j = 0; j < NOBJ_; ++j) {
    float4 c4 = *(const float4*)&conv[(size_t)j * V_ + vc];
    float cv[4] = {c4.x, c4.y, c4.z, c4.w};
    #pragma unroll
    for (int i = 0; i < 4; ++i) {
      float av = alS[(ty * 4 + i) * 97 + j];
      #pragma unroll
      for (int jjx = 0; jjx < 4; ++jjx) acc2[i][jjx] += av * cv[jjx];
    }
  }
  if (vq + 3 < V_) {
    float4 lb4 = *(const float4*)&linb[vq];
    float lb[4] = {lb4.x, lb4.y, lb4.z, lb4.w};
    #pragma unroll
    for (int i = 0; i < 4; ++i) {
      int row = ty * 4 + i;
      float pg = pg_s[row];
      float4 o;
      o.x = pg * (acc1[i][0] + lb[0]) + (1.0f - pg) * acc2[i][0];
      o.y = pg * (acc1[i][1] + lb[1]) + (1.0f - pg) * acc2[i][1];
      o.z = pg * (acc1[i][2] + lb[2]) + (1.0f - pg) * acc2[i][2];
      o.w = pg * (acc1[i][3] + lb[3]) + (1.0f - pg) * acc2[i][3];
      *(float4*)&out[(size_t)(n0 + row) * V_ + vq] = o;
    }
  }
}

extern "C" void kernel_launch(void* const* d_in, const int* in_sizes, int n_in,
                              void* d_out, int out_size, void* d_ws, size_t ws_size,
                              hipStream_t stream) {
  const float* features = (const float*)d_in[0];
  const int*   captions = (const int*)d_in[1];
  const int*   enc_in   = (const int*)d_in[3];
  const float* enc_out  = (const float*)d_in[4];
  const float* embed_W  = (const float*)d_in[5];
  const float* W_ih     = (const float*)d_in[6];
  const float* W_hh     = (const float*)d_in[7];
  const float* b_ih     = (const float*)d_in[8];
  const float* b_hh     = (const float*)d_in[9];
  const float* linear_W = (const float*)d_in[10];
  const float* linear_b = (const float*)d_in[11];
  const float* attn_W   = (const float*)d_in[12];
  const float* attn_b   = (const float*)d_in[13];
  const float* pge_W    = (const float*)d_in[14];
  const float* pge_b    = (const float*)d_in[15];
  const float* pgd_W    = (const float*)d_in[16];
  const float* pgd_b    = (const float*)d_in[17];
  const float* conv     = (const float*)d_in[18];
  float* out = (float*)d_out;

  float* ws   = (float*)d_ws;
  float* X    = ws;                  // 1024*256
  float* Xg   = X    + 262144;       // 1024*2048
  float* hTb  = Xg   + 2097152;      // 2*512*32
  float* hsb  = hTb  + 32768;        // 1024*512
  float* qws  = hsb  + 524288;       // 1024*256
  float* alp  = qws  + 262144;       // 1024*96
  float* pgn  = alp  + 98304;        // 1024
  unsigned* bar = (unsigned*)(pgn + 1024);   // 2 words: cnt, gen

  hipMemsetAsync(bar, 0, 2 * sizeof(unsigned), stream);
  k_gather <<<1024, 256, 0, stream>>>(features, captions, embed_W, X);
  k_gemm_bt<<<dim3(32, 16), 256, 0, stream>>>(X, W_ih, b_ih, b_hh, Xg, NROWS, G4_, EMB_);
  {
    const float* Xg_c = Xg;
    const float* Whh_c = W_hh;
    float* hTb_p = hTb;
    float* hsb_p = hsb;
    unsigned* cnt_p = bar;
    unsigned* gen_p = bar + 1;
    void* args[] = { (void*)&Xg_c, (void*)&Whh_c, (void*)&hTb_p, (void*)&hsb_p,
                     (void*)&cnt_p, (void*)&gen_p };
    hipLaunchCooperativeKernel((const void*)k_lstm_coop, dim3(256), dim3(256),
                               args, 0, stream);
  }
  k_gemm_bt<<<dim3(4, 16), 256, 0, stream>>>(hsb, attn_W, attn_b, nullptr, qws, NROWS, EMB_, HID_);
  k_attn   <<<1024, 256, 0, stream>>>(hsb, qws, enc_out, enc_in, pge_W, pge_b, pgd_W, pgd_b, alp, pgn);
  k_out    <<<dim3(469, 16), 256, 0, stream>>>(hsb, linear_W, linear_b, conv, alp, pgn, out);
}